// Round 6
// baseline (365.471 us; speedup 1.0000x reference)
//
#include <hip/hip_runtime.h>
#include <stdint.h>

#define DD 128
#define LDSROW 136  // 128 cols + 8 pad (ushort) -> 272B row stride, minimal b128 bank aliasing

typedef __attribute__((ext_vector_type(8))) short short8;
typedef __attribute__((ext_vector_type(4))) float float4v;

// ---------- bf16 helpers (RTNE) ----------
__device__ __forceinline__ unsigned short f2bf(float f) {
  unsigned u = __float_as_uint(f);
  unsigned r = u + 0x7fffu + ((u >> 16) & 1u);
  return (unsigned short)(r >> 16);
}
__device__ __forceinline__ unsigned pack2(float a, float b) {
  return (unsigned)f2bf(a) | ((unsigned)f2bf(b) << 16);
}
__device__ __forceinline__ float2 unpack2(unsigned p) {
  float2 r;
  r.x = __uint_as_float(p << 16);
  r.y = __uint_as_float(p & 0xffff0000u);
  return r;
}

// ---------- CSR build ----------
__global__ __launch_bounds__(256) void k_deg(const int* __restrict__ dst, int* deg, int e) {
  int i = blockIdx.x * 256 + threadIdx.x;
  if (i < e) atomicAdd(&deg[dst[i]], 1);
}

__global__ __launch_bounds__(1024) void k_scan1(const int* __restrict__ deg, int* __restrict__ incl,
                                                int* __restrict__ bsum, int n) {
  __shared__ int sh[1024];
  int t = threadIdx.x;
  int i = blockIdx.x * 1024 + t;
  int v = (i < n) ? deg[i] : 0;
  sh[t] = v;
  __syncthreads();
#pragma unroll
  for (int off = 1; off < 1024; off <<= 1) {
    int add = (t >= off) ? sh[t - off] : 0;
    __syncthreads();
    sh[t] += add;
    __syncthreads();
  }
  if (i < n) incl[i] = sh[t];
  if (t == 1023) bsum[blockIdx.x] = sh[1023];
}

// scan3 with fused block-sum scan (removes old k_scan2 dispatch)
__global__ __launch_bounds__(1024) void k_scan3(const int* __restrict__ deg, const int* __restrict__ incl,
                                                const int* __restrict__ bsum, int* __restrict__ rowstart,
                                                int* __restrict__ cursor, int n, int nb) {
  __shared__ int sboff;
  int t = threadIdx.x;
  if (t < 64) {
    int orig = (t < nb) ? bsum[t] : 0;
    int v = orig;
#pragma unroll
    for (int off = 1; off < 64; off <<= 1) {
      int u = __shfl_up(v, off);
      if (t >= off) v += u;
    }
    if (t == (int)blockIdx.x) sboff = v - orig;  // exclusive offset of this block
  }
  __syncthreads();
  int i = blockIdx.x * 1024 + t;
  if (i >= n) return;
  int d = deg[i];
  int excl = sboff + incl[i] - d;
  rowstart[i] = excl;
  cursor[i] = excl;
  if (i == n - 1) rowstart[n] = excl + d;
}

// ---------- range-partitioned fill (XCD-local write windows) ----------
__global__ __launch_bounds__(256) void k_fill_r(const int* __restrict__ src, const int* __restrict__ dst,
                                                int* cursor, int* __restrict__ esrc, int e, int rstep) {
  int range = blockIdx.x & 7;
  int i = (blockIdx.x >> 3) * 256 + threadIdx.x;
  if (i >= e) return;
  int d = dst[i];
  int lo = range * rstep;
  if (d >= lo && d < lo + rstep) {
    int p = atomicAdd(&cursor[d], 1);
    esrc[p] = src[i];
  }
}

// ---------- weight prep: fp32 [k][n] -> bf16 fragment-major for mfma_16x16x32 B-operand ----------
__global__ __launch_bounds__(256) void k_prep_w(const float* __restrict__ W1, const float* __restrict__ W2,
                                                const float* __restrict__ Wself, const float* __restrict__ Wneigh,
                                                unsigned* __restrict__ wfrag) {
  int gid = blockIdx.x * 256 + threadIdx.x;  // 0 .. 65536
  int m = gid >> 13;
  int r = gid & 8191;
  int p = r & 3;
  int lane = (r >> 2) & 63;
  int t = (r >> 8) & 3;
  int c = r >> 10;
  const float* W;
  if (m == 0) W = W1;
  else if (m == 1) W = W2;
  else if (m < 5) W = Wself + (size_t)(m - 2) * DD * DD;
  else W = Wneigh + (size_t)(m - 5) * DD * DD;
  int n = c * 16 + (lane & 15);
  int k = t * 32 + (lane >> 4) * 8 + 2 * p;
  wfrag[gid] = pack2(W[(size_t)k * DD + n], W[(size_t)(k + 1) * DD + n]);
}

// ---------- fused fc_in: out = tanh(h@W1+b1)@W2+b2  (bf16 out), 64 rows/block ----------
__global__ __launch_bounds__(256) void k_fc12(const float* __restrict__ h,
                                              const uint4* __restrict__ wf1, const uint4* __restrict__ wf2,
                                              const float* __restrict__ b1, const float* __restrict__ b2,
                                              unsigned short* __restrict__ outbf, int n) {
  __shared__ unsigned short sT[64 * LDSROW];
  int tid = threadIdx.x, w = tid >> 6, lane = tid & 63;
  int q = lane >> 4, nn = lane & 15;
  int r0 = (blockIdx.x * 4 + w) * 16;
  int rr = r0 + nn; if (rr >= n) rr = n - 1;
  // GEMM 1: A from global fp32
  short8 a[4];
  {
    const float* X = h + (size_t)rr * DD;
#pragma unroll
    for (int t = 0; t < 4; ++t) {
      int k0 = t * 32 + q * 8;
      float4 f0 = *(const float4*)&X[k0];
      float4 f1 = *(const float4*)&X[k0 + 4];
      uint4 u;
      u.x = pack2(f0.x, f0.y); u.y = pack2(f0.z, f0.w);
      u.z = pack2(f1.x, f1.y); u.w = pack2(f1.z, f1.w);
      a[t] = __builtin_bit_cast(short8, u);
    }
  }
  float4v acc[8];
#pragma unroll
  for (int c = 0; c < 8; ++c) acc[c] = (float4v){0.f, 0.f, 0.f, 0.f};
#pragma unroll
  for (int c = 0; c < 8; ++c) {
#pragma unroll
    for (int t = 0; t < 4; ++t) {
      short8 b = __builtin_bit_cast(short8, wf1[(c * 4 + t) * 64 + lane]);
      acc[c] = __builtin_amdgcn_mfma_f32_16x16x32_bf16(a[t], b, acc[c], 0, 0, 0);
    }
  }
  // tanh + transpose to LDS (A-fragment source layout for GEMM 2)
#pragma unroll
  for (int c = 0; c < 8; ++c) {
    float bc = b1[c * 16 + nn];
#pragma unroll
    for (int g = 0; g < 4; ++g) {
      int lr = w * 16 + q * 4 + g;
      sT[lr * LDSROW + c * 16 + nn] = f2bf(tanhf(acc[c][g] + bc));
    }
  }
  __syncthreads();
  // GEMM 2: A from LDS
  short8 a2[4];
#pragma unroll
  for (int t = 0; t < 4; ++t) {
    const uint4* p = (const uint4*)&sT[(w * 16 + nn) * LDSROW + (t * 4 + q) * 8];
    a2[t] = __builtin_bit_cast(short8, *p);
  }
  float4v acc2[8];
#pragma unroll
  for (int c = 0; c < 8; ++c) acc2[c] = (float4v){0.f, 0.f, 0.f, 0.f};
#pragma unroll
  for (int c = 0; c < 8; ++c) {
#pragma unroll
    for (int t = 0; t < 4; ++t) {
      short8 b = __builtin_bit_cast(short8, wf2[(c * 4 + t) * 64 + lane]);
      acc2[c] = __builtin_amdgcn_mfma_f32_16x16x32_bf16(a2[t], b, acc2[c], 0, 0, 0);
    }
  }
#pragma unroll
  for (int c = 0; c < 8; ++c) {
    float bc = b2[c * 16 + nn];
#pragma unroll
    for (int g = 0; g < 4; ++g) {
      int row = r0 + q * 4 + g;
      if (row < n) outbf[(size_t)row * DD + c * 16 + nn] = f2bf(acc2[c][g] + bc);
    }
  }
}

// ---------- fused SAGE layer: gather mean -> LDS, then act(X@Ws + b + G@Wn), 64 rows/block ----------
// ACT: 1 tanh, 2 silu
template <int ACT, bool OUTF32>
__global__ __launch_bounds__(256) void k_layer(const uint4* __restrict__ X,
                                               const int* __restrict__ rowstart, const int* __restrict__ esrc,
                                               const uint4* __restrict__ wfs, const uint4* __restrict__ wfn,
                                               const float* __restrict__ bias, void* __restrict__ outp, int n) {
  __shared__ unsigned short sT[64 * LDSROW];
  int tid = threadIdx.x, w = tid >> 6, lane = tid & 63;
  int q = lane >> 4, nn = lane & 15;
  int blk0 = blockIdx.x * 64;
  // ---- gather phase: wave w aggregates its own 16 rows into LDS ----
  for (int p = 0; p < 16; ++p) {
    int lr = w * 16 + p;
    int r = blk0 + lr;
    if (r < n) {
      int ru = __builtin_amdgcn_readfirstlane(r);
      int beg = rowstart[ru], end = rowstart[ru + 1];
      int cnt = end - beg;
      float acc8[8];
#pragma unroll
      for (int i = 0; i < 8; ++i) acc8[i] = 0.f;
      int base = 0;
      for (; base + 16 <= cnt; base += 16) {  // 4 gathers in flight per group
        int j = beg + base + q;
        int s0 = esrc[j], s1 = esrc[j + 4], s2 = esrc[j + 8], s3 = esrc[j + 12];
        uint4 v0 = X[(size_t)s0 * 16 + nn];
        uint4 v1 = X[(size_t)s1 * 16 + nn];
        uint4 v2 = X[(size_t)s2 * 16 + nn];
        uint4 v3 = X[(size_t)s3 * 16 + nn];
        const unsigned* u0 = (const unsigned*)&v0;
        const unsigned* u1 = (const unsigned*)&v1;
        const unsigned* u2 = (const unsigned*)&v2;
        const unsigned* u3 = (const unsigned*)&v3;
#pragma unroll
        for (int k = 0; k < 4; ++k) {
          float2 f0 = unpack2(u0[k]), f1 = unpack2(u1[k]);
          float2 f2 = unpack2(u2[k]), f3 = unpack2(u3[k]);
          acc8[2 * k]     += (f0.x + f1.x) + (f2.x + f3.x);
          acc8[2 * k + 1] += (f0.y + f1.y) + (f2.y + f3.y);
        }
      }
      for (; base + 4 <= cnt; base += 4) {
        int s = esrc[beg + base + q];
        uint4 v = X[(size_t)s * 16 + nn];
        const unsigned* u = (const unsigned*)&v;
#pragma unroll
        for (int k = 0; k < 4; ++k) {
          float2 f = unpack2(u[k]);
          acc8[2 * k] += f.x;
          acc8[2 * k + 1] += f.y;
        }
      }
      if (base + q < cnt) {
        int s = esrc[beg + base + q];
        uint4 v = X[(size_t)s * 16 + nn];
        const unsigned* u = (const unsigned*)&v;
#pragma unroll
        for (int k = 0; k < 4; ++k) {
          float2 f = unpack2(u[k]);
          acc8[2 * k] += f.x;
          acc8[2 * k + 1] += f.y;
        }
      }
#pragma unroll
      for (int k = 0; k < 8; ++k) {
        acc8[k] += __shfl_xor(acc8[k], 16, 64);
        acc8[k] += __shfl_xor(acc8[k], 32, 64);
      }
      if (q == 0) {
        float inv = 1.0f / (float)(cnt > 1 ? cnt : 1);
        uint4 o;
        o.x = pack2(acc8[0] * inv, acc8[1] * inv);
        o.y = pack2(acc8[2] * inv, acc8[3] * inv);
        o.z = pack2(acc8[4] * inv, acc8[5] * inv);
        o.w = pack2(acc8[6] * inv, acc8[7] * inv);
        *(uint4*)&sT[lr * LDSROW + nn * 8] = o;
      }
    }
  }
  __syncthreads();
  // ---- GEMM phase ----
  int r0 = blk0 + w * 16;
  int rr = r0 + nn; if (rr >= n) rr = n - 1;
  short8 a[4], g[4];
  {
    const uint4* Xr = X + (size_t)rr * 16;
#pragma unroll
    for (int t = 0; t < 4; ++t) {
      a[t] = __builtin_bit_cast(short8, Xr[t * 4 + q]);
      const uint4* p = (const uint4*)&sT[(w * 16 + nn) * LDSROW + (t * 4 + q) * 8];
      g[t] = __builtin_bit_cast(short8, *p);
    }
  }
  float4v acc[8];
#pragma unroll
  for (int c = 0; c < 8; ++c) acc[c] = (float4v){0.f, 0.f, 0.f, 0.f};
#pragma unroll
  for (int c = 0; c < 8; ++c) {
#pragma unroll
    for (int t = 0; t < 4; ++t) {
      short8 b = __builtin_bit_cast(short8, wfs[(c * 4 + t) * 64 + lane]);
      acc[c] = __builtin_amdgcn_mfma_f32_16x16x32_bf16(a[t], b, acc[c], 0, 0, 0);
    }
#pragma unroll
    for (int t = 0; t < 4; ++t) {
      short8 b = __builtin_bit_cast(short8, wfn[(c * 4 + t) * 64 + lane]);
      acc[c] = __builtin_amdgcn_mfma_f32_16x16x32_bf16(g[t], b, acc[c], 0, 0, 0);
    }
  }
#pragma unroll
  for (int c = 0; c < 8; ++c) {
    float bc = bias[c * 16 + nn];
#pragma unroll
    for (int gg = 0; gg < 4; ++gg) {
      int row = r0 + q * 4 + gg;
      if (row < n) {
        float v = acc[c][gg] + bc;
        if (ACT == 1) v = tanhf(v);
        else v = v / (1.f + __expf(-v));
        if (OUTF32) ((float*)outp)[(size_t)row * DD + c * 16 + nn] = v;
        else ((unsigned short*)outp)[(size_t)row * DD + c * 16 + nn] = f2bf(v);
      }
    }
  }
}

extern "C" void kernel_launch(void* const* d_in, const int* in_sizes, int n_in,
                              void* d_out, int out_size, void* d_ws, size_t ws_size,
                              hipStream_t stream) {
  const float* h_in = (const float*)d_in[0];
  const int* src    = (const int*)d_in[1];
  const int* dst    = (const int*)d_in[2];
  const float* W1   = (const float*)d_in[3];
  const float* b1   = (const float*)d_in[4];
  const float* W2   = (const float*)d_in[5];
  const float* b2   = (const float*)d_in[6];
  const float* Wself  = (const float*)d_in[7];
  const float* bself  = (const float*)d_in[8];
  const float* Wneigh = (const float*)d_in[9];
  const int N = in_sizes[0] / DD;
  const int E = in_sizes[1];
  float* out = (float*)d_out;

  char* ws = (char*)d_ws;
  size_t off = 0;
  auto alloc = [&](size_t bytes) -> char* {
    char* p = ws + off;
    off = (off + bytes + 255) & ~(size_t)255;
    return p;
  };
  unsigned* wfrag = (unsigned*)alloc(8 * 32768);               // 8 matrices, frag-major bf16
  unsigned* actA  = (unsigned*)alloc((size_t)N * 64 * 4);      // bf16 [N][128]
  unsigned* actB  = (unsigned*)alloc((size_t)N * 64 * 4);
  int* esrc     = (int*)alloc((size_t)E * 4);
  int* degi     = (int*)alloc((size_t)N * 4);
  int* rowstart = (int*)alloc((size_t)(N + 1) * 4);
  int* cursor   = (int*)alloc((size_t)N * 4);
  int* incl     = (int*)alloc((size_t)N * 4);
  int* bsum     = (int*)alloc(65 * 4);

  hipMemsetAsync(degi, 0, (size_t)N * 4, stream);
  const int eb = (E + 255) / 256;
  const int nb = (N + 1023) / 1024;  // 49 <= 64
  const int rstep = (N + 7) / 8;
  k_deg<<<eb, 256, 0, stream>>>(dst, degi, E);
  k_scan1<<<nb, 1024, 0, stream>>>(degi, incl, bsum, N);
  k_scan3<<<nb, 1024, 0, stream>>>(degi, incl, bsum, rowstart, cursor, N, nb);
  k_fill_r<<<eb * 8, 256, 0, stream>>>(src, dst, cursor, esrc, E, rstep);
  k_prep_w<<<256, 256, 0, stream>>>(W1, W2, Wself, Wneigh, wfrag);

  const int gb = (N + 63) / 64;
  const uint4* wf = (const uint4*)wfrag;  // 2048 uint4 per matrix

  // fused fc_in -> actB (bf16)
  k_fc12<<<gb, 256, 0, stream>>>(h_in, wf + 0 * 2048, wf + 1 * 2048, b1, b2,
                                 (unsigned short*)actB, N);

  const unsigned* cur = actB;
  unsigned* nxt = actA;
  for (int l = 0; l < 3; ++l) {
    const uint4* wsF = wf + (size_t)(2 + l) * 2048;
    const uint4* wnF = wf + (size_t)(5 + l) * 2048;
    const float* bs = bself + (size_t)l * DD;
    if (l < 2) {
      k_layer<2, false><<<gb, 256, 0, stream>>>((const uint4*)cur, rowstart, esrc, wsF, wnF, bs, nxt, N);
      const unsigned* tmp = cur;
      cur = nxt;
      nxt = (unsigned*)tmp;
    } else {
      k_layer<1, true><<<gb, 256, 0, stream>>>((const uint4*)cur, rowstart, esrc, wsF, wnF, bs, out, N);
    }
  }
}